// Round 7
// baseline (83.514 us; speedup 1.0000x reference)
//
#include <hip/hip_runtime.h>

#define NODES 512
#define WORDS 16          // 512 bits / 32
#define NBATCH 32
#define SENTINEL 11       // MAX_DISTANCE + 1
#define NEMB 12           // MAX_DISTANCE + 2
#define NOUT 8
#define G 4               // sources per BFS block

// ---------------------------------------------------------------------------
// K1: pack adjacency bits, one u32 word (32 elements, 8x float4) per thread.
// node_mask (int32 on upload) ballot-packed into LDS once per block.
// ---------------------------------------------------------------------------
__global__ void __launch_bounds__(256)
pack_bits(const float* __restrict__ A, const int* __restrict__ mask,
          unsigned int* __restrict__ bitA) {
    const int tid = blockIdx.x * 256 + threadIdx.x;   // 262144 words total
    const int t = threadIdx.x;
    const int w = tid & 15;
    const int i = (tid >> 4) & 511;
    const int b = tid >> 13;                          // constant per block

    __shared__ unsigned int s_mw[WORDS];
    {
        bool m0 = mask[b * NODES + t] != 0;
        bool m1 = mask[b * NODES + 256 + t] != 0;
        unsigned long long b0 = __ballot(m0);
        unsigned long long b1 = __ballot(m1);
        if ((t & 63) == 0) {
            int wv = t >> 6;
            s_mw[2 * wv]         = (unsigned int)b0;
            s_mw[2 * wv + 1]     = (unsigned int)(b0 >> 32);
            s_mw[8 + 2 * wv]     = (unsigned int)b1;
            s_mw[8 + 2 * wv + 1] = (unsigned int)(b1 >> 32);
        }
    }

    const float4* p = (const float4*)(A + (size_t)tid * 32);
    unsigned int bits = 0;
#pragma unroll
    for (int q = 0; q < 8; ++q) {
        float4 v = p[q];
        bits |= (v.x > 0.5f ? 1u : 0u) << (4 * q);
        bits |= (v.y > 0.5f ? 1u : 0u) << (4 * q + 1);
        bits |= (v.z > 0.5f ? 1u : 0u) << (4 * q + 2);
        bits |= (v.w > 0.5f ? 1u : 0u) << (4 * q + 3);
    }
    __syncthreads();
    bool rv = (s_mw[i >> 5] >> (i & 31)) & 1u;
    bitA[tid] = rv ? (bits & s_mw[w]) : 0u;
}

// ---------------------------------------------------------------------------
// K2: symmetrize: adj[b,i,w] |= transpose bits (1 MB, L2-resident).
// ---------------------------------------------------------------------------
__global__ void __launch_bounds__(256)
symmetrize(const unsigned int* __restrict__ bitA, unsigned int* __restrict__ adjb) {
    int tid = blockIdx.x * 256 + threadIdx.x;   // total B*N*WORDS = 262144
    int w = tid & 15;
    int i = (tid >> 4) & 511;
    int b = tid >> 13;
    const unsigned int* base = bitA + (size_t)b * NODES * WORDS;
    unsigned int word = base[i * WORDS + w];
    unsigned int t = 0;
    int iw = i >> 5, ib = i & 31;
#pragma unroll
    for (int k = 0; k < 32; ++k) {
        t |= ((base[(32 * w + k) * WORDS + iw] >> ib) & 1u) << k;
    }
    adjb[tid] = word | t;
}

// ---------------------------------------------------------------------------
// K3: fused bitset-BFS + embedding store. Block = (G=4 sources, batch),
// 512 threads. Adjacency matrix lives in LDS (32 KB) -> tiny VGPR live set,
// packed per-source state (dists: 4 bytes in a u32; reach/new: bitmasks).
// __launch_bounds__(512,8): 64-VGPR cap now FITS (round-5 spilled because
// the 16-reg adj row was resident) -> 4 blocks/CU so neighbor blocks' store
// streams hide the BFS + epilogue phases. Double-buffered frontier, one
// barrier per hop; early exit on empty frontier or saturation.
// Epilogue: s_dist transposed to [column] = packed u32 of 4 source dists ->
// conflict-free b32 LDS traffic; 8 lane-contiguous float4 stores.
// ---------------------------------------------------------------------------
__global__ void __launch_bounds__(512, 8)
bfs_store(const unsigned int* __restrict__ adjb, const int* __restrict__ mask,
          const float* __restrict__ emb, float4* __restrict__ out4) {
    const int i0 = blockIdx.x * G;
    const int b = blockIdx.y;
    const int j = threadIdx.x;

    __shared__ unsigned int s_adj[NODES][WORDS];   // 32 KB
    __shared__ unsigned int s_f[2][G][WORDS];
    __shared__ unsigned int s_state[2][8];         // bit0 anyNew, bit1 allDone
    __shared__ unsigned int s_dist[NODES];         // packed: byte s = dist[s] of column
    __shared__ __align__(16) float s_emb[NEMB * NOUT];

    if (j < NEMB * NOUT) s_emb[j] = emb[j];

    // stage symmetric adjacency row j into LDS (64 B)
    {
        const uint4* rowp = (const uint4*)(adjb + ((size_t)b * NODES + j) * WORDS);
        uint4* dst = (uint4*)&s_adj[j][0];
        dst[0] = rowp[0]; dst[1] = rowp[1]; dst[2] = rowp[2]; dst[3] = rowp[3];
    }

    const bool valid_j = (mask[b * NODES + j] != 0);

    if (j < G * WORDS) {
        int s = j >> 4, w = j & 15;
        int i = i0 + s;
        bool v = (mask[b * NODES + i] != 0);
        s_f[0][s][w] = (v && (i >> 5) == w) ? (1u << (i & 31)) : 0u;
    }

    unsigned int dists = 0x0B0B0B0Bu;   // SENTINEL in every byte
    unsigned int reachm = 0;
#pragma unroll
    for (int s = 0; s < G; ++s) {
        if ((j == i0 + s) && valid_j) {
            dists &= ~(0xffu << (8 * s));   // dist 0
            reachm |= 1u << s;
        }
    }
    __syncthreads();

    int p = 0;
    for (int t = 1; t <= 10; ++t) {
        const uint4* a4 = (const uint4*)&s_adj[j][0];
        uint4 a0 = a4[0], a1 = a4[1], a2 = a4[2], a3 = a4[3];
        unsigned int newm = 0;
#pragma unroll
        for (int s = 0; s < G; ++s) {
            const uint4* f4 = (const uint4*)s_f[p][s];
            uint4 f0 = f4[0], f1 = f4[1], f2 = f4[2], f3 = f4[3];
            unsigned int hit =
                (a0.x & f0.x) | (a0.y & f0.y) | (a0.z & f0.z) | (a0.w & f0.w) |
                (a1.x & f1.x) | (a1.y & f1.y) | (a1.z & f1.z) | (a1.w & f1.w) |
                (a2.x & f2.x) | (a2.y & f2.y) | (a2.z & f2.z) | (a2.w & f2.w) |
                (a3.x & f3.x) | (a3.y & f3.y) | (a3.z & f3.z) | (a3.w & f3.w);
            if (hit && !((reachm >> s) & 1u)) newm |= 1u << s;
        }
        unsigned long long anyb = 0;
        unsigned long long doneb = ~0ull;
#pragma unroll
        for (int s = 0; s < G; ++s) {
            unsigned long long bal = __ballot((newm >> s) & 1u);
            anyb |= bal;
            doneb &= __ballot((((reachm | newm) >> s) & 1u) || !valid_j);
            if ((j & 63) == 0) {
                int wv = j >> 6;
                s_f[p ^ 1][s][2 * wv]     = (unsigned int)bal;
                s_f[p ^ 1][s][2 * wv + 1] = (unsigned int)(bal >> 32);
            }
        }
#pragma unroll
        for (int s = 0; s < G; ++s) {
            if ((newm >> s) & 1u)
                dists = (dists & ~(0xffu << (8 * s))) | ((unsigned int)t << (8 * s));
        }
        reachm |= newm;
        if ((j & 63) == 0) {
            s_state[p ^ 1][j >> 6] =
                ((anyb != 0ull) ? 1u : 0u) | ((doneb == ~0ull) ? 2u : 0u);
        }
        __syncthreads();   // next frontier + state visible; old buffer free
        p ^= 1;
        unsigned int anyw = 0, donew = 2;
#pragma unroll
        for (int wv = 0; wv < 8; ++wv) {
            unsigned int st = s_state[p][wv];
            anyw |= st;
            donew &= st;
        }
        if (!(anyw & 1u) || (donew & 2u)) break;
    }

    // Epilogue: column-major packed dist, conflict-free b32 LDS traffic.
    s_dist[j] = dists;
    __syncthreads();   // also orders the s_emb writes from kernel start

    const float4* e4 = (const float4*)s_emb;
    unsigned int dw0 = s_dist[j >> 1];          // column j/2      (h=0)
    unsigned int dw1 = s_dist[256 + (j >> 1)];  // column 256+j/2  (h=1)
    const int half = j & 1;
    size_t base0 = ((size_t)b * NODES + i0) * (NODES * NOUT / 4); // 1024 f4/row
#pragma unroll
    for (int s = 0; s < G; ++s) {
        int d0 = (dw0 >> (8 * s)) & 0xff;
        int d1 = (dw1 >> (8 * s)) & 0xff;
        out4[base0 + (size_t)s * 1024 + j]       = e4[2 * d0 + half];
        out4[base0 + (size_t)s * 1024 + 512 + j] = e4[2 * d1 + half];
    }
}

// ---------------------------------------------------------------------------
extern "C" void kernel_launch(void* const* d_in, const int* in_sizes, int n_in,
                              void* d_out, int out_size, void* d_ws, size_t ws_size,
                              hipStream_t stream) {
    const float* adjacency = (const float*)d_in[0];
    const int* node_mask = (const int*)d_in[1];   // bool -> int32 on upload
    const float* emb = (const float*)d_in[2];
    float4* out4 = (float4*)d_out;

    unsigned int* bitA = (unsigned int*)d_ws;                       // 1 MB
    unsigned int* adjb = bitA + (size_t)NBATCH * NODES * WORDS;     // 1 MB

    // K1: 262144 words -> 1024 blocks (each thread packs 32 adjacency elems)
    pack_bits<<<1024, 256, 0, stream>>>(adjacency, node_mask, bitA);
    // K2: 262144 words -> 1024 blocks
    symmetrize<<<1024, 256, 0, stream>>>(bitA, adjb);
    // K3: one block per (4 sources, batch); fused BFS + store
    bfs_store<<<dim3(NODES / G, NBATCH), 512, 0, stream>>>(adjb, node_mask, emb, out4);
}

// Round 8
// 79.210 us; speedup vs baseline: 1.0543x; 1.0543x over previous
//
#include <hip/hip_runtime.h>

#define NODES 512
#define WORDS 16          // 512 bits / 32
#define NBATCH 32
#define SENTINEL 11       // MAX_DISTANCE + 1
#define NEMB 12           // MAX_DISTANCE + 2
#define NOUT 8
#define G 2               // sources per BFS block (G=2 -> 64-VGPR fits)

// ---------------------------------------------------------------------------
// K1: pack adjacency bits, one u32 word (32 elements, 8x float4) per thread.
// node_mask (int32 on upload) ballot-packed into LDS once per block.
// ---------------------------------------------------------------------------
__global__ void __launch_bounds__(256)
pack_bits(const float* __restrict__ A, const int* __restrict__ mask,
          unsigned int* __restrict__ bitA) {
    const int tid = blockIdx.x * 256 + threadIdx.x;   // 262144 words total
    const int t = threadIdx.x;
    const int w = tid & 15;
    const int i = (tid >> 4) & 511;
    const int b = tid >> 13;                          // constant per block

    __shared__ unsigned int s_mw[WORDS];
    {
        bool m0 = mask[b * NODES + t] != 0;
        bool m1 = mask[b * NODES + 256 + t] != 0;
        unsigned long long b0 = __ballot(m0);
        unsigned long long b1 = __ballot(m1);
        if ((t & 63) == 0) {
            int wv = t >> 6;
            s_mw[2 * wv]         = (unsigned int)b0;
            s_mw[2 * wv + 1]     = (unsigned int)(b0 >> 32);
            s_mw[8 + 2 * wv]     = (unsigned int)b1;
            s_mw[8 + 2 * wv + 1] = (unsigned int)(b1 >> 32);
        }
    }

    const float4* p = (const float4*)(A + (size_t)tid * 32);
    unsigned int bits = 0;
#pragma unroll
    for (int q = 0; q < 8; ++q) {
        float4 v = p[q];
        bits |= (v.x > 0.5f ? 1u : 0u) << (4 * q);
        bits |= (v.y > 0.5f ? 1u : 0u) << (4 * q + 1);
        bits |= (v.z > 0.5f ? 1u : 0u) << (4 * q + 2);
        bits |= (v.w > 0.5f ? 1u : 0u) << (4 * q + 3);
    }
    __syncthreads();
    bool rv = (s_mw[i >> 5] >> (i & 31)) & 1u;
    bitA[tid] = rv ? (bits & s_mw[w]) : 0u;
}

// ---------------------------------------------------------------------------
// K2: symmetrize: adj[b,i,w] |= transpose bits (1 MB, L2-resident).
// ---------------------------------------------------------------------------
__global__ void __launch_bounds__(256)
symmetrize(const unsigned int* __restrict__ bitA, unsigned int* __restrict__ adjb) {
    int tid = blockIdx.x * 256 + threadIdx.x;   // total B*N*WORDS = 262144
    int w = tid & 15;
    int i = (tid >> 4) & 511;
    int b = tid >> 13;
    const unsigned int* base = bitA + (size_t)b * NODES * WORDS;
    unsigned int word = base[i * WORDS + w];
    unsigned int t = 0;
    int iw = i >> 5, ib = i & 31;
#pragma unroll
    for (int k = 0; k < 32; ++k) {
        t |= ((base[(32 * w + k) * WORDS + iw] >> ib) & 1u) << k;
    }
    adjb[tid] = word | t;
}

// ---------------------------------------------------------------------------
// K3: fused bitset-BFS + embedding store. Block = (G=2 sources, batch),
// 512 threads; thread j holds symmetric adjacency row j in 16 VGPRs
// (adjacency in LDS was round 7: 64B stride = heavy ds_read_b128 bank
// conflicts; VGPR-resident won). G=2 shrinks the live set to ~55 regs so
// the __launch_bounds__(512,8) 64-VGPR cap fits WITHOUT spills (round 5's
// G=4 spilled at this cap) -> 4 blocks/CU: neighbor blocks' store streams
// hide each block's adj-load/BFS/epilogue phases. Double-buffered frontier,
// one barrier/hop; early exit on empty frontier or saturation (1 ballot).
// ---------------------------------------------------------------------------
__global__ void __launch_bounds__(512, 8)
bfs_store(const unsigned int* __restrict__ adjb, const int* __restrict__ mask,
          const float* __restrict__ emb, float4* __restrict__ out4) {
    const int i0 = blockIdx.x * G;
    const int b = blockIdx.y;
    const int j = threadIdx.x;

    __shared__ unsigned int s_f[2][G][WORDS];
    __shared__ unsigned int s_state[2][8];   // bit0 anyNew, bit1 allDone
    __shared__ unsigned int s_dist[NODES];   // byte s = dist[source s] of column
    __shared__ __align__(16) float s_emb[NEMB * NOUT];

    if (j < NEMB * NOUT) s_emb[j] = emb[j];

    // adjacency row j (64 B) in VGPRs
    const uint4* rowp = (const uint4*)(adjb + ((size_t)b * NODES + j) * WORDS);
    uint4 ar0 = rowp[0], ar1 = rowp[1], ar2 = rowp[2], ar3 = rowp[3];

    const bool valid_j = (mask[b * NODES + j] != 0);

    if (j < G * WORDS) {
        int s = j >> 4, w = j & 15;
        int i = i0 + s;
        bool v = (mask[b * NODES + i] != 0);
        s_f[0][s][w] = (v && (i >> 5) == w) ? (1u << (i & 31)) : 0u;
    }

    unsigned int dists = 0x0B0Bu;     // SENTINEL in both used bytes
    unsigned int reachm = 0;
#pragma unroll
    for (int s = 0; s < G; ++s) {
        if ((j == i0 + s) && valid_j) {
            dists &= ~(0xffu << (8 * s));   // dist 0
            reachm |= 1u << s;
        }
    }
    __syncthreads();

    int p = 0;
    for (int t = 1; t <= 10; ++t) {
        unsigned int newm = 0;
#pragma unroll
        for (int s = 0; s < G; ++s) {
            const uint4* f4 = (const uint4*)s_f[p][s];
            uint4 f0 = f4[0], f1 = f4[1], f2 = f4[2], f3 = f4[3];
            unsigned int hit =
                (ar0.x & f0.x) | (ar0.y & f0.y) | (ar0.z & f0.z) | (ar0.w & f0.w) |
                (ar1.x & f1.x) | (ar1.y & f1.y) | (ar1.z & f1.z) | (ar1.w & f1.w) |
                (ar2.x & f2.x) | (ar2.y & f2.y) | (ar2.z & f2.z) | (ar2.w & f2.w) |
                (ar3.x & f3.x) | (ar3.y & f3.y) | (ar3.z & f3.z) | (ar3.w & f3.w);
            if (hit && !((reachm >> s) & 1u)) newm |= 1u << s;
        }
        unsigned long long bal0 = __ballot(newm & 1u);
        unsigned long long bal1 = __ballot((newm >> 1) & 1u);
        bool alldone = (((reachm | newm) == 3u) || !valid_j);
        unsigned long long balD = __ballot(alldone);
        if ((j & 63) == 0) {
            int wv = j >> 6;
            s_f[p ^ 1][0][2 * wv]     = (unsigned int)bal0;
            s_f[p ^ 1][0][2 * wv + 1] = (unsigned int)(bal0 >> 32);
            s_f[p ^ 1][1][2 * wv]     = (unsigned int)bal1;
            s_f[p ^ 1][1][2 * wv + 1] = (unsigned int)(bal1 >> 32);
            s_state[p ^ 1][wv] = (((bal0 | bal1) != 0ull) ? 1u : 0u) |
                                 ((balD == ~0ull) ? 2u : 0u);
        }
#pragma unroll
        for (int s = 0; s < G; ++s) {
            if ((newm >> s) & 1u)
                dists = (dists & ~(0xffu << (8 * s))) | ((unsigned int)t << (8 * s));
        }
        reachm |= newm;
        __syncthreads();   // next frontier + state visible; old buffer free
        p ^= 1;
        unsigned int anyw = 0, donew = 2;
#pragma unroll
        for (int wv = 0; wv < 8; ++wv) {
            unsigned int st = s_state[p][wv];
            anyw |= st;
            donew &= st;
        }
        if (!(anyw & 1u) || (donew & 2u)) break;
    }

    // Epilogue: column-major packed dist, conflict-free b32 LDS traffic,
    // then 4 lane-contiguous float4 stores (2 per source row).
    s_dist[j] = dists;
    __syncthreads();   // also orders the s_emb writes from kernel start

    const float4* e4 = (const float4*)s_emb;
    unsigned int dw0 = s_dist[j >> 1];          // column j/2      (k=j)
    unsigned int dw1 = s_dist[256 + (j >> 1)];  // column 256+j/2  (k=512+j)
    const int half = j & 1;
    size_t base0 = ((size_t)b * NODES + i0) * (NODES * NOUT / 4); // 1024 f4/row
#pragma unroll
    for (int s = 0; s < G; ++s) {
        int d0 = (dw0 >> (8 * s)) & 0xff;
        int d1 = (dw1 >> (8 * s)) & 0xff;
        out4[base0 + (size_t)s * 1024 + j]       = e4[2 * d0 + half];
        out4[base0 + (size_t)s * 1024 + 512 + j] = e4[2 * d1 + half];
    }
}

// ---------------------------------------------------------------------------
extern "C" void kernel_launch(void* const* d_in, const int* in_sizes, int n_in,
                              void* d_out, int out_size, void* d_ws, size_t ws_size,
                              hipStream_t stream) {
    const float* adjacency = (const float*)d_in[0];
    const int* node_mask = (const int*)d_in[1];   // bool -> int32 on upload
    const float* emb = (const float*)d_in[2];
    float4* out4 = (float4*)d_out;

    unsigned int* bitA = (unsigned int*)d_ws;                       // 1 MB
    unsigned int* adjb = bitA + (size_t)NBATCH * NODES * WORDS;     // 1 MB

    // K1: 262144 words -> 1024 blocks (each thread packs 32 adjacency elems)
    pack_bits<<<1024, 256, 0, stream>>>(adjacency, node_mask, bitA);
    // K2: 262144 words -> 1024 blocks
    symmetrize<<<1024, 256, 0, stream>>>(bitA, adjb);
    // K3: one block per (2 sources, batch); fused BFS + store
    bfs_store<<<dim3(NODES / G, NBATCH), 512, 0, stream>>>(adjb, node_mask, emb, out4);
}